// Round 6
// baseline (35.020 us; speedup 1.0000x reference)
//
#include <hip/hip_runtime.h>

#define BATCH 8
#define NUM_GENES 20000
#define FEAT 64

// Pass 1: find segment start offsets from sorted segment_ids.
__global__ __launch_bounds__(256)
void find_starts_kernel(const int* __restrict__ segment_ids,
                        int* __restrict__ starts, int total)
{
    int i = blockIdx.x * 256 + threadIdx.x;
    if (i < total) {
        int s = segment_ids[i];
        if (i == 0 || segment_ids[i - 1] != s) starts[s] = i;
    }
}

// Pass 2: 256-thread blocks = 4 waves; wave w handles segment group*4+w,
// all for the SAME batch b = bid & 7 (XCD pinning: verified R2, FETCH
// 157->70 MB). lane = sub*16 + fq; sub picks one of 4 gene rows per
// gather instruction, fq the float4 feature quad.
//
// Double-buffered depth-8 software pipeline (verified lever, R5: depth-8
// issue-then-drain got 43->32.6 us): chunk c+1's 8 loads are issued
// BEFORE accumulating chunk c, so the wave keeps 8-16 gathers in flight
// continuously instead of draining to zero each chunk.
//
// Indices are staged pre-scaled to element offsets (idx*FEAT, < 2^21 so
// 32-bit safe): per-load address = one __shfl + 32-bit add.

#define ISSUE_CHUNK(BUF, C)                                                   \
    {                                                                         \
        const int kbase = (C) * 8;                                            \
        _Pragma("unroll")                                                     \
        for (int p = 0; p < 8; ++p) {                                         \
            const int j = sub + 4 * (kbase + p);                              \
            const int off = (j < 64) ? __shfl(off_a, j) : __shfl(off_b, j & 63); \
            if (j < cnt) {                                                    \
                BUF[p] = *reinterpret_cast<const float4*>(gbase + off);       \
            } else {                                                          \
                BUF[p] = make_float4(0.f, 0.f, 0.f, 0.f);                     \
            }                                                                 \
        }                                                                     \
    }

#define ACCUM_CHUNK(BUF)                                                      \
    {                                                                         \
        _Pragma("unroll")                                                     \
        for (int p = 0; p < 8; ++p) {                                         \
            acc.x += BUF[p].x; acc.y += BUF[p].y;                             \
            acc.z += BUF[p].z; acc.w += BUF[p].w;                             \
        }                                                                     \
    }

__global__ __launch_bounds__(256)
void genesets_pool_kernel(const float* __restrict__ gene,        // [B][G][F]
                          const int*   __restrict__ flat_indices,// [total]
                          const int*   __restrict__ starts,      // [S]
                          const int*   __restrict__ counts,      // [S]
                          float*       __restrict__ out,         // [B][S][F]
                          int num_segments)
{
    const int bid  = blockIdx.x;
    const int b    = bid & 7;                      // batch -> XCD
    const int wave = threadIdx.x >> 6;
    const int s    = (bid >> 3) * 4 + wave;        // segment
    const int lane = threadIdx.x & 63;
    const int sub  = lane >> 4;                    // 0..3
    const int fq   = lane & 15;                    // feature quad

    if (s >= num_segments) return;

    const int start = starts[s];
    const int cnt   = counts[s];

    // Stage all indices, pre-scaled to element offsets (cnt < 128).
    int off_a = (lane      < cnt) ? flat_indices[start + lane]      * FEAT : 0;
    int off_b = (lane + 64 < cnt) ? flat_indices[start + lane + 64] * FEAT : 0;

    const float* gbase = gene + (size_t)b * NUM_GENES * FEAT + fq * 4;

    float4 acc = make_float4(0.f, 0.f, 0.f, 0.f);
    const int kn      = (cnt + 3) >> 2;            // quads, <= 23
    const int nchunks = (kn + 7) >> 3;             // <= 3

    float4 bufA[8], bufB[8];

    ISSUE_CHUNK(bufA, 0)
    if (nchunks > 1) {
        ISSUE_CHUNK(bufB, 1)
        ACCUM_CHUNK(bufA)
        if (nchunks > 2) {
            ISSUE_CHUNK(bufA, 2)
            ACCUM_CHUNK(bufB)
            ACCUM_CHUNK(bufA)
        } else {
            ACCUM_CHUNK(bufB)
        }
    } else {
        ACCUM_CHUNK(bufA)
    }

    // Reduce over the 4 sub-groups (lanes differing in bits 4..5).
    acc.x += __shfl_xor(acc.x, 16); acc.y += __shfl_xor(acc.y, 16);
    acc.z += __shfl_xor(acc.z, 16); acc.w += __shfl_xor(acc.w, 16);
    acc.x += __shfl_xor(acc.x, 32); acc.y += __shfl_xor(acc.y, 32);
    acc.z += __shfl_xor(acc.z, 32); acc.w += __shfl_xor(acc.w, 32);

    if (sub == 0) {
        const float inv = 1.0f / (float)cnt;
        float4 r = make_float4(acc.x * inv, acc.y * inv, acc.z * inv, acc.w * inv);
        *reinterpret_cast<float4*>(out + ((size_t)b * num_segments + s) * FEAT + fq * 4) = r;
    }
}

extern "C" void kernel_launch(void* const* d_in, const int* in_sizes, int n_in,
                              void* d_out, int out_size, void* d_ws, size_t ws_size,
                              hipStream_t stream)
{
    const float* gene         = (const float*)d_in[0];
    const int*   flat_indices = (const int*)d_in[1];
    const int*   segment_ids  = (const int*)d_in[2];
    const int*   counts       = (const int*)d_in[3];
    float*       out          = (float*)d_out;

    const int total        = in_sizes[1];
    const int num_segments = in_sizes[3];

    int* starts = (int*)d_ws;          // num_segments ints of scratch

    find_starts_kernel<<<(total + 255) / 256, 256, 0, stream>>>(segment_ids, starts, total);

    const int seg_groups = (num_segments + 3) / 4;
    const int nblocks    = seg_groups * BATCH;
    genesets_pool_kernel<<<nblocks, 256, 0, stream>>>(gene, flat_indices, starts,
                                                      counts, out, num_segments);
}

// Round 7
// 33.322 us; speedup vs baseline: 1.0509x; 1.0509x over previous
//
#include <hip/hip_runtime.h>

#define BATCH 8
#define NUM_GENES 20000
#define FEAT 64

// Pass 1: find segment start offsets from sorted segment_ids.
__global__ __launch_bounds__(256)
void find_starts_kernel(const int* __restrict__ segment_ids,
                        int* __restrict__ starts, int total)
{
    int i = blockIdx.x * 256 + threadIdx.x;
    if (i < total) {
        int s = segment_ids[i];
        if (i == 0 || segment_ids[i - 1] != s) starts[s] = i;
    }
}

// Pass 2: 256-thread blocks = 4 waves; wave w handles segment group*4+w,
// all for the SAME batch b = bid & 7 (XCD pinning: verified R2, FETCH
// 157->70 MB). lane = sub*16 + fq; sub picks one of 4 gene rows per
// gather instruction, fq the float4 feature quad.
//
// Gather pipeline: single-buffer sawtooth, depth 12 (R5 showed depth 4->8
// = -25%; R6 showed double-buffering regresses via register liveness).
// kn <= 23 so exactly 2 chunks of 12 cover any segment.
__global__ __launch_bounds__(256)
void genesets_pool_kernel(const float* __restrict__ gene,        // [B][G][F]
                          const int*   __restrict__ flat_indices,// [total]
                          const int*   __restrict__ starts,      // [S]
                          const int*   __restrict__ counts,      // [S]
                          float*       __restrict__ out,         // [B][S][F]
                          int num_segments)
{
    const int bid  = blockIdx.x;
    const int b    = bid & 7;                      // batch -> XCD
    const int wave = threadIdx.x >> 6;
    const int s    = (bid >> 3) * 4 + wave;        // segment
    const int lane = threadIdx.x & 63;
    const int sub  = lane >> 4;                    // 0..3
    const int fq   = lane & 15;                    // feature quad

    if (s >= num_segments) return;

    const int start = starts[s];
    const int cnt   = counts[s];

    // Stage all indices, pre-scaled to element offsets (cnt < 128).
    int off_a = (lane      < cnt) ? flat_indices[start + lane]      * FEAT : 0;
    int off_b = (lane + 64 < cnt) ? flat_indices[start + lane + 64] * FEAT : 0;

    const float* gbase = gene + (size_t)b * NUM_GENES * FEAT + fq * 4;

    float4 acc = make_float4(0.f, 0.f, 0.f, 0.f);

    #pragma unroll 1
    for (int c = 0; c < 24; c += 12) {             // 2 chunks cover kn <= 23
        float4 buf[12];
        #pragma unroll
        for (int p = 0; p < 12; ++p) {
            const int j = sub + 4 * (c + p);
            const int off = (j < 64) ? __shfl(off_a, j) : __shfl(off_b, j & 63);
            if (j < cnt) {
                buf[p] = *reinterpret_cast<const float4*>(gbase + off);
            } else {
                buf[p] = make_float4(0.f, 0.f, 0.f, 0.f);
            }
        }
        #pragma unroll
        for (int p = 0; p < 12; ++p) {
            acc.x += buf[p].x; acc.y += buf[p].y;
            acc.z += buf[p].z; acc.w += buf[p].w;
        }
        if (4 * (c + 12) >= cnt) break;            // uniform across wave
    }

    // Reduce over the 4 sub-groups (lanes differing in bits 4..5).
    acc.x += __shfl_xor(acc.x, 16); acc.y += __shfl_xor(acc.y, 16);
    acc.z += __shfl_xor(acc.z, 16); acc.w += __shfl_xor(acc.w, 16);
    acc.x += __shfl_xor(acc.x, 32); acc.y += __shfl_xor(acc.y, 32);
    acc.z += __shfl_xor(acc.z, 32); acc.w += __shfl_xor(acc.w, 32);

    if (sub == 0) {
        const float inv = 1.0f / (float)cnt;
        float4 r = make_float4(acc.x * inv, acc.y * inv, acc.z * inv, acc.w * inv);
        *reinterpret_cast<float4*>(out + ((size_t)b * num_segments + s) * FEAT + fq * 4) = r;
    }
}

extern "C" void kernel_launch(void* const* d_in, const int* in_sizes, int n_in,
                              void* d_out, int out_size, void* d_ws, size_t ws_size,
                              hipStream_t stream)
{
    const float* gene         = (const float*)d_in[0];
    const int*   flat_indices = (const int*)d_in[1];
    const int*   segment_ids  = (const int*)d_in[2];
    const int*   counts       = (const int*)d_in[3];
    float*       out          = (float*)d_out;

    const int total        = in_sizes[1];
    const int num_segments = in_sizes[3];

    int* starts = (int*)d_ws;          // num_segments ints of scratch

    find_starts_kernel<<<(total + 255) / 256, 256, 0, stream>>>(segment_ids, starts, total);

    const int seg_groups = (num_segments + 3) / 4;
    const int nblocks    = seg_groups * BATCH;
    genesets_pool_kernel<<<nblocks, 256, 0, stream>>>(gene, flat_indices, starts,
                                                      counts, out, num_segments);
}